// Round 12
// baseline (139.438 us; speedup 1.0000x reference)
//
#include <hip/hip_runtime.h>
#include <hip/hip_bf16.h>

typedef unsigned short u16;
typedef __attribute__((ext_vector_type(8))) short bf16x8;
typedef __attribute__((ext_vector_type(4))) float f32x4;
typedef __attribute__((ext_vector_type(8))) unsigned short u16x8;

#define GLDS(gp, lp) __builtin_amdgcn_global_load_lds( \
    (const __attribute__((address_space(1))) void*)(gp), \
    (__attribute__((address_space(3))) void*)(lp), 16, 0, 0)

__device__ __forceinline__ u16 f2b(float f) {
  unsigned u = __builtin_bit_cast(unsigned, f);
  return (u16)((u + 0x7fffu + ((u >> 16) & 1u)) >> 16);  // RNE, finite inputs
}
__device__ __forceinline__ float b2f(u16 s) {
  return __builtin_bit_cast(float, (unsigned)s << 16);
}

#define BARX() do { __builtin_amdgcn_sched_barrier(0); \
  asm volatile("s_barrier" ::: "memory"); \
  __builtin_amdgcn_sched_barrier(0); } while (0)

// ---------- kernel 0: f32 -> bf16 conversion (x, Wp|Wc|Ws packed, Wo) ----------
__global__ __launch_bounds__(256) void convert_k(
    const float* __restrict__ x, const float* __restrict__ Wp,
    const float* __restrict__ Wc, const float* __restrict__ Ws,
    const float* __restrict__ Wo, u16* __restrict__ xb,
    u16* __restrict__ wall, u16* __restrict__ wob)
{
  const long CX = 2097152;  // 16777216/8 x-chunks
  const long CW = 98304;    // 786432/8 packed-weight chunks
  const long CO = 32768;    // 262144/8 Wo chunks
  const long total = CX + CW + CO;
  for (long i = (long)blockIdx.x * blockDim.x + threadIdx.x; i < total;
       i += (long)gridDim.x * blockDim.x) {
    const float* src; u16* dst;
    if (i < CX) {
      src = x + i * 8; dst = xb + i * 8;
    } else if (i < CX + CW) {
      long e = (i - CX) * 8;
      int n = (int)(e >> 9), k = (int)(e & 511);
      const float* wr = (n < 512)  ? (Wp + (long)n * 512)
                      : (n < 1024) ? (Wc + (long)(n - 512) * 512)
                                   : (Ws + (long)(n - 1024) * 512);
      src = wr + k; dst = wall + e;
    } else {
      long e = (i - CX - CW) * 8; src = Wo + e; dst = wob + e;
    }
    f32x4 v0 = *(const f32x4*)src;
    f32x4 v1 = *(const f32x4*)(src + 4);
    u16x8 o;
    o[0]=f2b(v0[0]); o[1]=f2b(v0[1]); o[2]=f2b(v0[2]); o[3]=f2b(v0[3]);
    o[4]=f2b(v1[0]); o[5]=f2b(v1[1]); o[6]=f2b(v1[2]); o[7]=f2b(v1[3]);
    *(u16x8*)dst = o;
  }
}

// ---------- 128x128 GEMM, 4 waves, small-wave TLP structure: C = A·Bw^T + bias ----------
// A: [M][512] bf16, Bw: [NC][512] bf16. 256 thr = 4 waves (2x2), 64x64/wave,
// acc 64 AGPR -> ~3 waves/SIMD, 2-3 blocks/CU (cross-block overlap hides drains).
// LDS 32 KiB: single-buffered A,B tiles [128][128B], XOR-granule swizzle both-sides.
// Per tile: vmcnt(0)+bar; read 16 frags; lgkm0+bar (bufs free); stage t+1; 32 MFMA.
// LDS-sliced epilogue (r10-verified pattern, acc[4][4]).
template<int NC, bool BF16OUT>
__global__ __launch_bounds__(256, 3) void gemmT(
    const u16* __restrict__ A, const u16* __restrict__ Bw,
    const float* __restrict__ bias0, const float* __restrict__ bias1,
    const float* __restrict__ bias2, void* __restrict__ Cout)
{
  __shared__ alignas(16) char smem[32768];
  char* sAc = smem;            // [128 rows][128 B]
  char* sBc = smem + 16384;

  const int tid = threadIdx.x;
  const int w = tid >> 6, lane = tid & 63;
  const int wr = w >> 1, wc = w & 1;          // 2 x 2 wave grid
  const int ln15 = lane & 15, g4 = lane >> 4, l7 = lane & 7;

  // --- block swizzle: XCD-chunked bijective (nwg % 8 == 0 for both) ---
  const int nbx = NC / 128;
  const int nwg = nbx * 256;
  const int qq = nwg / 8;
  const int flat = blockIdx.x;
  const int swz = (flat & 7) * qq + (flat >> 3);
  const int bx = swz % nbx, by = swz / nbx;
  const long row0 = (long)by * 128;
  const int col0 = bx * 128;

  // --- staging (r10-verified formula family): pre-swizzled global source,
  // linear LDS dest. Site j covers rows j*32 + t8; slot s of row r holds
  // global K-granule s ^ (r&7)  ((j*32+t8)&7 == t8&7).
  const int t8 = tid >> 3;                    // 0..31
  const int gsw = (tid & 7) ^ (t8 & 7);
  const u16* pA = A + (row0 + t8) * 512 + gsw * 8;
  const u16* pB = Bw + ((long)col0 + t8) * 512 + gsw * 8;

#define STG(tt) do { \
    const u16* a_ = pA + (tt) * 64; const u16* b_ = pB + (tt) * 64; \
    char* da_ = sAc + w * 1024; char* db_ = sBc + w * 1024; \
    GLDS(a_, da_);                GLDS(a_ + 16384, da_ + 4096); \
    GLDS(a_ + 32768, da_ + 8192); GLDS(a_ + 49152, da_ + 12288); \
    GLDS(b_, db_);                GLDS(b_ + 16384, db_ + 4096); \
    GLDS(b_ + 32768, db_ + 8192); GLDS(b_ + 49152, db_ + 12288); \
  } while (0)

  // --- fragment reads (swizzled): row = (wr*64|wc*64) + mf*16 + ln15, row&7 == l7 ---
  const int gkb0 = (g4 ^ l7) << 4;          // kk=0 swizzled granule byte
  const int gkb1 = ((g4 + 4) ^ l7) << 4;    // kk=1
  const char* fA = sAc + (wr * 64 + ln15) * 128;
  const char* fB = sBc + (wc * 64 + ln15) * 128;

  f32x4 acc[4][4] = {};

  STG(0);
  for (int t = 0; t < 8; ++t) {          // K = 512 / BK = 64
    bf16x8 aF[4][2], bF[4][2];
    asm volatile("s_waitcnt vmcnt(0)" ::: "memory");  // tile t landed (own GLDS)
    BARX();                                           // visible to all waves
#pragma unroll
    for (int mf = 0; mf < 4; ++mf) {
      aF[mf][0] = *(const bf16x8*)(fA + mf * 2048 + gkb0);
      aF[mf][1] = *(const bf16x8*)(fA + mf * 2048 + gkb1);
    }
#pragma unroll
    for (int nf = 0; nf < 4; ++nf) {
      bF[nf][0] = *(const bf16x8*)(fB + nf * 2048 + gkb0);
      bF[nf][1] = *(const bf16x8*)(fB + nf * 2048 + gkb1);
    }
    asm volatile("s_waitcnt lgkmcnt(0)" ::: "memory");  // frags in regs
    BARX();                                             // buffers free, all waves
    if (t < 7) STG(t + 1);
    __builtin_amdgcn_sched_barrier(0);   // pin GLDS issue above the MFMA cluster
    __builtin_amdgcn_s_setprio(1);
#pragma unroll
    for (int mf = 0; mf < 4; ++mf)
#pragma unroll
      for (int nf = 0; nf < 4; ++nf) {
        f32x4 c_ = acc[mf][nf];
        c_ = __builtin_amdgcn_mfma_f32_16x16x32_bf16(aF[mf][0], bF[nf][0], c_, 0, 0, 0);
        c_ = __builtin_amdgcn_mfma_f32_16x16x32_bf16(aF[mf][1], bF[nf][1], c_, 0, 0, 0);
        acc[mf][nf] = c_;
      }
    __builtin_amdgcn_s_setprio(0);
  }

  // ---- epilogue (r10-verified pattern): per-wave 8 KB LDS slice -> full-line stores ----
  // acc[mf][n][j]: local row = mf*16 + g4*4 + j (0..63), local col = n*16 + ln15.
  __syncthreads();
  const long rgb = row0 + wr * 64;
  const int cgb = col0 + wc * 64;
  if (BF16OUT) {
    u16* sc = (u16*)(smem + (w << 13));      // 8 KiB/wave: [64][64] u16, 1 pass
#pragma unroll
    for (int n = 0; n < 4; ++n) {
      const int colg = cgb + ln15 + n * 16;
      const float* bp_ = (NC == 512) ? bias0
                         : (colg < 512 ? bias0 : (colg < 1024 ? bias1 : bias2));
      const float bv = bp_[colg & 511];
      const int c = ln15 + n * 16;
      const int gsl = c >> 3, co = c & 7;
#pragma unroll
      for (int mf = 0; mf < 4; ++mf)
#pragma unroll
        for (int j = 0; j < 4; ++j) {
          const int r = mf * 16 + (g4 << 2) + j;   // 0..63
          sc[r * 64 + (((gsl ^ (r & 7)) << 3) | co)] = f2b(acc[mf][n][j] + bv);
        }
    }
    asm volatile("s_waitcnt lgkmcnt(0)" ::: "memory");
    __builtin_amdgcn_sched_barrier(0);
#pragma unroll
    for (int it = 0; it < 8; ++it) {
      const int rr = it * 8 + (lane >> 3);
      const int gl = lane & 7;
      u16x8 v = *(const u16x8*)(sc + rr * 64 + ((gl ^ (rr & 7)) << 3));
      *(u16x8*)((u16*)Cout + (rgb + rr) * NC + cgb + gl * 8) = v;
    }
  } else {
    float* scf = (float*)(smem + (w << 13));  // 8 KiB/wave: [32][64] f32, 2 passes
#pragma unroll
    for (int q = 0; q < 2; ++q) {             // rows q*32 .. q*32+31
#pragma unroll
      for (int n = 0; n < 4; ++n) {
        const int colg = cgb + ln15 + n * 16;
        const float bv = bias0[colg & 511];
        const int c = ln15 + n * 16;
        const int gsl = c >> 2, co = c & 3;
#pragma unroll
        for (int mh = 0; mh < 2; ++mh)
#pragma unroll
          for (int j = 0; j < 4; ++j) {
            const int r = mh * 16 + (g4 << 2) + j;  // 0..31 within slice
            scf[r * 64 + (((gsl ^ (r & 7)) << 2) | co)] = acc[q * 2 + mh][n][j] + bv;
          }
      }
      asm volatile("s_waitcnt lgkmcnt(0)" ::: "memory");
      __builtin_amdgcn_sched_barrier(0);
#pragma unroll
      for (int it = 0; it < 8; ++it) {
        const int rr = it * 4 + (lane >> 4);
        const int gl = lane & 15;
        f32x4 v = *(const f32x4*)(scf + rr * 64 + ((gl ^ (rr & 7)) << 2));
        *(f32x4*)((float*)Cout + (rgb + q * 32 + rr) * NC + cgb + gl * 4) = v;
      }
      asm volatile("s_waitcnt lgkmcnt(0)" ::: "memory");
      __builtin_amdgcn_sched_barrier(0);
    }
  }
#undef STG
}

// ---------- attention: per-token 8x8 head-mix, one wave per token ----------
__global__ __launch_bounds__(256) void attn_k(const u16* __restrict__ PCS,
                                              u16* __restrict__ OUT)
{
  // per-wave f32 scratch: p[8][68], c[8][68], s[512], attn[64]  (pad 68 kills bank conflicts)
  __shared__ float L[4][1664];
  const int w = threadIdx.x >> 6, lane = threadIdx.x & 63;
  const long token = (long)blockIdx.x * 4 + w;
  float* Lw = L[w];
  const int C0 = 544, S0 = 1088, AT0 = 1600;
  const u16* rowp = PCS + token * 1536;
#pragma unroll
  for (int q = 0; q < 3; ++q) {
    u16x8 v = *(const u16x8*)(rowp + q * 512 + lane * 8);
    float* dst = (q < 2) ? (Lw + q * 544 + (lane >> 3) * 68 + (lane & 7) * 8)
                         : (Lw + S0 + lane * 8);
    f32x4 a = {b2f(v[0]), b2f(v[1]), b2f(v[2]), b2f(v[3])};
    f32x4 b = {b2f(v[4]), b2f(v[5]), b2f(v[6]), b2f(v[7])};
    *(f32x4*)dst = a;
    *(f32x4*)(dst + 4) = b;
  }
  // all data wave-local: no __syncthreads needed (wave-synchronous + in-order DS)
  const int h = lane >> 3, t = lane & 7;
  float sc = 0.f;
#pragma unroll
  for (int d = 0; d < 64; d += 4) {
    f32x4 pv = *(const f32x4*)(Lw + h * 68 + d);
    f32x4 cv = *(const f32x4*)(Lw + C0 + t * 68 + d);
    sc += pv[0]*cv[0] + pv[1]*cv[1] + pv[2]*cv[2] + pv[3]*cv[3];
  }
  sc *= 0.125f;  // 1/sqrt(D), D=64
  float mx = sc;
  mx = fmaxf(mx, __shfl_xor(mx, 1));
  mx = fmaxf(mx, __shfl_xor(mx, 2));
  mx = fmaxf(mx, __shfl_xor(mx, 4));
  float e = __expf(sc - mx);
  float sm = e;
  sm += __shfl_xor(sm, 1);
  sm += __shfl_xor(sm, 2);
  sm += __shfl_xor(sm, 4);
  Lw[AT0 + lane] = e / sm;
  float o[8] = {0, 0, 0, 0, 0, 0, 0, 0};
#pragma unroll
  for (int tt = 0; tt < 8; ++tt) {
    const float av = Lw[AT0 + h * 8 + tt];
    f32x4 s0 = *(const f32x4*)(Lw + S0 + tt * 64 + t * 8);
    f32x4 s1 = *(const f32x4*)(Lw + S0 + tt * 64 + t * 8 + 4);
    o[0] += av * s0[0]; o[1] += av * s0[1]; o[2] += av * s0[2]; o[3] += av * s0[3];
    o[4] += av * s1[0]; o[5] += av * s1[1]; o[6] += av * s1[2]; o[7] += av * s1[3];
  }
  u16x8 ov;
#pragma unroll
  for (int j = 0; j < 8; ++j) ov[j] = f2b(o[j]);
  // out element index within token = h*64 + (t*8+j) = lane*8+j -> coalesced 16B/lane
  *(u16x8*)(OUT + token * 512 + lane * 8) = ov;
}

extern "C" void kernel_launch(void* const* d_in, const int* in_sizes, int n_in,
                              void* d_out, int out_size, void* d_ws, size_t ws_size,
                              hipStream_t stream) {
  const float* x  = (const float*)d_in[0];
  const float* Wp = (const float*)d_in[1];
  const float* bp = (const float*)d_in[2];
  const float* Wc = (const float*)d_in[3];
  const float* bc = (const float*)d_in[4];
  const float* Ws = (const float*)d_in[5];
  const float* bs = (const float*)d_in[6];
  const float* Wo = (const float*)d_in[7];
  const float* bo = (const float*)d_in[8];

  char* ws = (char*)d_ws;
  u16* xb   = (u16*)ws;                      // 33,554,432 B  (x as bf16)
  u16* wall = (u16*)(ws + 33554432);         //  1,572,864 B  ([1536][512] Wp|Wc|Ws)
  u16* wob  = (u16*)(ws + 35127296);         //    524,288 B  ([512][512] Wo)
  u16* pcs  = (u16*)(ws + 35651584);         // 100,663,296 B ([32768][1536] p|c|s)
  u16* outb = xb;                            // overlay: xb dead after gemm1

  convert_k<<<2048, 256, 0, stream>>>(x, Wp, Wc, Ws, Wo, xb, wall, wob);
  gemmT<1536, true><<<3072, 256, 0, stream>>>(xb, wall, bp, bc, bs, pcs);
  attn_k<<<8192, 256, 0, stream>>>(pcs, outb);
  gemmT<512, false><<<1024, 256, 0, stream>>>(outb, wob, bo, bo, bo, d_out);
}